// Round 13
// baseline (248.470 us; speedup 1.0000x reference)
//
#include <hip/hip_runtime.h>
#include <hip/hip_bf16.h>
#include <math.h>

#define H3 768

// ---- ws layout (floats), ~4.74 MB ----
#define OFF_Q     0u        // 2048*256  (proj K-half 0)
#define OFF_K     524288u   // 128*256
#define OFF_UVK   557056u   // 128*512
#define OFF_SQ    622592u   // 2176 row sums (q rows 0..2047, k rows at 2048+bj)
#define OFF_SQ2   624768u   // 2176
#define OFF_WGU   626944u   // 256
#define OFF_WGV   627200u   // 256
#define OFF_CU    627456u   // 256
#define OFF_CV    627712u   // 256
#define OFF_Q2    627968u   // 2048*256  (proj K-half 1)
#define OFF_K2    1152256u  // 128*256   end 1185024

// ---- scratch inside d_out's bias region (2097152 floats), all consumed
// before topk_bias overwrites it ----
#define BO_UVQ   0u          // 1048576  (2048x512 fp32)
#define BO_WQF   1048576u    // 262144   (Wq frags hi/lo, NTG=16, K=1024)
#define BO_WKF   1310720u    // 262144
#define BO_BPK   1572864u    // 131072   (qk-weight frags, NTG=32, K=256)
#define BO_WQBF  1703936u    // 131072
#define BO_WKBF  1835008u    // 131072   end 1966080 < 2097152

typedef __attribute__((ext_vector_type(8))) short bf16x8;
typedef __attribute__((ext_vector_type(4))) float f32x4;

__device__ __forceinline__ float bf2f(short s) {
    return __uint_as_float(((unsigned)(unsigned short)s) << 16);
}
union bfu { __hip_bfloat162 h; short2 s; };
__device__ __forceinline__ void split2(float a, float b, short* hi2, short* lo2) {
    bfu h; h.h = __float22bfloat162_rn(float2{a, b});
    float fa = bf2f(h.s.x), fb = bf2f(h.s.y);
    bfu l; l.h = __float22bfloat162_rn(float2{a - fa, b - fb});
    hi2[0] = h.s.x; hi2[1] = h.s.y;
    lo2[0] = l.s.x; lo2[1] = l.s.y;
}
__device__ __forceinline__ void split8(const float* v, bf16x8* vh, bf16x8* vl) {
    short h2[2], l2[2];
#pragma unroll
    for (int i = 0; i < 4; i++) {
        split2(v[2 * i], v[2 * i + 1], h2, l2);
        (*vh)[2 * i] = h2[0]; (*vh)[2 * i + 1] = h2[1];
        (*vl)[2 * i] = l2[0]; (*vl)[2 * i + 1] = l2[1];
    }
}

// branchless exact-gelu via A&S 7.1.26 erf (abs err ~1.5e-7)
__device__ __forceinline__ float gelu_fast(float v) {
    float ar = v * 0.70710678118654752440f;
    float a = fabsf(ar);
    float t = __builtin_amdgcn_rcpf(fmaf(0.3275911f, a, 1.0f));
    float p = fmaf(fmaf(fmaf(fmaf(1.061405429f, t, -1.453152027f), t,
                             1.421413741f), t, -0.284496736f), t, 0.254829592f) * t;
    float e = __expf(-ar * ar);
    float er = fmaf(-p, e, 1.0f);
    er = copysignf(er, ar);
    return 0.5f * v * (1.0f + er);
}

__device__ __forceinline__ float wave_reduce_add(float v) {
#pragma unroll
    for (int off = 32; off > 0; off >>= 1) v += __shfl_xor(v, off, 64);
    return v;
}

// ---- k1: prep — per-h scalars + weight frag scatters (split-bf16) ----
__global__ __launch_bounds__(256) void prep(const float* __restrict__ Wq,
                                            const float* __restrict__ Wk,
                                            const float* __restrict__ Wu,
                                            const float* __restrict__ Wv,
                                            const float* __restrict__ g,
                                            const float* __restrict__ lb,
                                            const float* __restrict__ bu,
                                            const float* __restrict__ bv,
                                            float* __restrict__ ws,
                                            float* __restrict__ bsc) {
    int tid = threadIdx.x;
    int bid = blockIdx.x;
    if (bid < 64) {
        int h = bid * 4 + (tid >> 6);
        int lane = tid & 63;
        float su = 0.f, sv = 0.f, tu = 0.f, tv = 0.f;
#pragma unroll
        for (int i = 0; i < 12; i++) {
            int c = lane + 64 * i;
            float gg = g[c], bb = lb[c];
            float wu = Wu[h * H3 + c], wv = Wv[h * H3 + c];
            su += wu * gg; sv += wv * gg; tu += wu * bb; tv += wv * bb;
        }
        su = wave_reduce_add(su); sv = wave_reduce_add(sv);
        tu = wave_reduce_add(tu); tv = wave_reduce_add(tv);
        if (lane == 0) {
            ws[OFF_WGU + h] = su; ws[OFF_WGV + h] = sv;
            ws[OFF_CU + h] = tu + bu[h]; ws[OFF_CV + h] = tv + bv[h];
        }
        return;
    }
    float v8[8];
    bf16x8 vh, vl;
    if (bid < 320) {
        // WqF (64..191) / WkF (192..319): N=256, K=1024, NTG=16
        const float* W; bf16x8* dst;
        int idx;
        if (bid < 192) { idx = (bid - 64) * 256 + tid; W = Wq; dst = (bf16x8*)(bsc + BO_WQF); }
        else { idx = (bid - 192) * 256 + tid; W = Wk; dst = (bf16x8*)(bsc + BO_WKF); }
        int n = idx >> 7, k8 = idx & 127;
        const float* src = W + (size_t)n * 1024 + k8 * 8;
        *(float4*)&v8[0] = *(const float4*)src;
        *(float4*)&v8[4] = *(const float4*)(src + 4);
        split8(v8, &vh, &vl);
        int kc = k8 >> 2, grp = k8 & 3, lane = grp * 16 + (n & 15), ntg = n >> 4;
        size_t s0 = ((size_t)(kc * 16 + ntg) * 2) * 64 + lane;
        dst[s0] = vh; dst[s0 + 64] = vl;
        return;
    }
    // N=512, K=256, NTG=32 frag matrices from Wu/Wv*g
    int idx, c0;
    bf16x8* dst;
    int n;
    if (bid < 384) {        // WQBf
        idx = (bid - 320) * 256 + tid;
        n = idx >> 5; c0 = (idx & 31) * 8;
        dst = (bf16x8*)(bsc + BO_WQBF);
    } else if (bid < 448) { // WKBf
        idx = (bid - 384) * 256 + tid;
        n = idx >> 5; c0 = 256 + (idx & 31) * 8;
        dst = (bf16x8*)(bsc + BO_WKBF);
    } else {                // BPK (interleaved U/V n-mapping)
        idx = (bid - 448) * 256 + tid;
        n = idx >> 5; c0 = 512 + (idx & 31) * 8;
        dst = (bf16x8*)(bsc + BO_BPK);
    }
    int h, uv;
    if (bid < 448) { uv = (n < 256) ? 0 : 1; h = (n < 256) ? n : n - 256; }
    else {
        int ntg0 = n >> 4, cc = n & 15;
        uv = ntg0 & 1;
        h = ((ntg0 >> 3) << 6) | (((ntg0 >> 1) & 3) << 4) | cc;
    }
    const float* W = uv ? Wv : Wu;
#pragma unroll
    for (int i = 0; i < 8; i++) v8[i] = W[(size_t)h * H3 + c0 + i] * g[c0 + i];
    split8(v8, &vh, &vl);
    int k8 = (c0 & 255) >> 3;
    int kc = k8 >> 2, grp = k8 & 3, lane = grp * 16 + (n & 15), ntg = n >> 4;
    size_t s0 = ((size_t)(kc * 32 + ntg) * 2) * 64 + lane;
    dst[s0] = vh; dst[s0 + 64] = vl;
}

// ---- k2: projection MFMA, K-split x2 writing disjoint halves (no atomics) ----
__global__ __launch_bounds__(256) void proj_mfma(const float* __restrict__ Q,
                                                 const float* __restrict__ Kin,
                                                 const float* __restrict__ bsc,
                                                 float* __restrict__ ws) {
    __shared__ __align__(16) short Ah[2][32 * 40], Al[2][32 * 40];
    int tid = threadIdx.x, bx = blockIdx.x, by = blockIdx.y, ks = blockIdx.z;
    const float* A; float* C; const bf16x8* BF;
    if (by < 64) {
        A = Q + (size_t)by * 32 * 1024;
        C = ws + (ks ? OFF_Q2 : OFF_Q) + (size_t)by * 32 * 256;
        BF = (const bf16x8*)(bsc + BO_WQF);
    } else {
        A = Kin + (size_t)(by - 64) * 32 * 1024;
        C = ws + (ks ? OFF_K2 : OFF_K) + (size_t)(by - 64) * 32 * 256;
        BF = (const bf16x8*)(bsc + BO_WKF);
    }
    int w = tid >> 6, l = tid & 63, c15 = l & 15, grp = l >> 4;
    int mt = w & 1, np = w >> 1;
    int srow = tid >> 3, scol = (tid & 7) * 4;
    const float* arow = A + (size_t)srow * 1024 + ks * 512 + scol;
    f32x4 acc[2];
    acc[0] = (f32x4){0.f, 0.f, 0.f, 0.f};
    acc[1] = (f32x4){0.f, 0.f, 0.f, 0.f};
    float4 a4 = *(const float4*)&arow[0];
    for (int kc = 0; kc < 16; kc++) {
        int pb = kc & 1;
        short h4[4], l4[4];
        split2(a4.x, a4.y, &h4[0], &l4[0]);
        split2(a4.z, a4.w, &h4[2], &l4[2]);
        int ao = srow * 40 + scol;
        *(short4*)&Ah[pb][ao] = *(short4*)&h4[0];
        *(short4*)&Al[pb][ao] = *(short4*)&l4[0];
        if (kc < 15) a4 = *(const float4*)&arow[(kc + 1) * 32];
        __syncthreads();
        int fo = (mt * 16 + c15) * 40 + grp * 8;
        bf16x8 afh = *(const bf16x8*)&Ah[pb][fo];
        bf16x8 afl = *(const bf16x8*)&Al[pb][fo];
        int kcg = ks * 16 + kc;
        bf16x8 bh[2], bl[2];
#pragma unroll
        for (int i = 0; i < 2; i++) {
            int ntg = bx * 4 + 2 * np + i;
            size_t fi = ((size_t)(kcg * 16 + ntg) * 2) * 64 + l;
            bh[i] = BF[fi]; bl[i] = BF[fi + 64];
        }
#pragma unroll
        for (int i = 0; i < 2; i++)
            acc[i] = __builtin_amdgcn_mfma_f32_16x16x32_bf16(afl, bh[i], acc[i], 0, 0, 0);
#pragma unroll
        for (int i = 0; i < 2; i++)
            acc[i] = __builtin_amdgcn_mfma_f32_16x16x32_bf16(afh, bl[i], acc[i], 0, 0, 0);
#pragma unroll
        for (int i = 0; i < 2; i++)
            acc[i] = __builtin_amdgcn_mfma_f32_16x16x32_bf16(afh, bh[i], acc[i], 0, 0, 0);
    }
#pragma unroll
    for (int r = 0; r < 4; r++) {
        int rloc = mt * 16 + grp * 4 + r;
#pragma unroll
        for (int i = 0; i < 2; i++)
            C[(size_t)rloc * 256 + bx * 64 + (2 * np + i) * 16 + c15] = acc[i][r];
    }
}

// ---- k3: UV GEMM via MFMA (sums the two proj halves) + fused row stats ----
__global__ __launch_bounds__(256) void uv_mfma(float* __restrict__ ws,
                                               float* __restrict__ bsc) {
    __shared__ __align__(16) short Ah[64 * 40], Al[64 * 40];
    int tid = threadIdx.x, bx = blockIdx.x, by = blockIdx.y;
    const float* A1; const float* A2; float* C; const bf16x8* BF; int sbase;
    if (by < 32) {
        A1 = ws + OFF_Q + (size_t)by * 64 * 256;
        A2 = ws + OFF_Q2 + (size_t)by * 64 * 256;
        C = bsc + BO_UVQ + (size_t)by * 64 * 512;
        BF = (const bf16x8*)(bsc + BO_WQBF);
        sbase = by * 64;
    } else {
        A1 = ws + OFF_K + (size_t)(by - 32) * 64 * 256;
        A2 = ws + OFF_K2 + (size_t)(by - 32) * 64 * 256;
        C = ws + OFF_UVK + (size_t)(by - 32) * 64 * 512;
        BF = (const bf16x8*)(bsc + BO_WKBF);
        sbase = 2048 + (by - 32) * 64;
    }
    int w = tid >> 6, l = tid & 63, c15 = l & 15, grp = l >> 4;
    int srow = tid >> 2, scol = (tid & 3) * 8;
    f32x4 acc[4];
#pragma unroll
    for (int nt = 0; nt < 4; nt++) acc[nt] = (f32x4){0.f, 0.f, 0.f, 0.f};
    float s1 = 0.f, s2 = 0.f;
    for (int kc = 0; kc < 8; kc++) {
        float v8[8], u8[8];
        const float* src1 = &A1[(size_t)srow * 256 + kc * 32 + scol];
        const float* src2 = &A2[(size_t)srow * 256 + kc * 32 + scol];
        *(float4*)&v8[0] = *(const float4*)src1;
        *(float4*)&v8[4] = *(const float4*)(src1 + 4);
        *(float4*)&u8[0] = *(const float4*)src2;
        *(float4*)&u8[4] = *(const float4*)(src2 + 4);
#pragma unroll
        for (int i = 0; i < 8; i++) v8[i] += u8[i];
        if (bx == 0) {
#pragma unroll
            for (int i = 0; i < 8; i++) { s1 += v8[i]; s2 = fmaf(v8[i], v8[i], s2); }
        }
        bf16x8 vh, vl;
        split8(v8, &vh, &vl);
        int ao = srow * 40 + scol;
        *(bf16x8*)&Ah[ao] = vh;
        *(bf16x8*)&Al[ao] = vl;
        __syncthreads();
        int fo = (w * 16 + c15) * 40 + grp * 8;
        bf16x8 afh = *(const bf16x8*)&Ah[fo];
        bf16x8 afl = *(const bf16x8*)&Al[fo];
        bf16x8 bh[4], bl[4];
#pragma unroll
        for (int nt = 0; nt < 4; nt++) {
            int ntg = bx * 4 + nt;
            size_t fi = ((size_t)(kc * 32 + ntg) * 2) * 64 + l;
            bh[nt] = BF[fi]; bl[nt] = BF[fi + 64];
        }
#pragma unroll
        for (int nt = 0; nt < 4; nt++)
            acc[nt] = __builtin_amdgcn_mfma_f32_16x16x32_bf16(afl, bh[nt], acc[nt], 0, 0, 0);
#pragma unroll
        for (int nt = 0; nt < 4; nt++)
            acc[nt] = __builtin_amdgcn_mfma_f32_16x16x32_bf16(afh, bl[nt], acc[nt], 0, 0, 0);
#pragma unroll
        for (int nt = 0; nt < 4; nt++)
            acc[nt] = __builtin_amdgcn_mfma_f32_16x16x32_bf16(afh, bh[nt], acc[nt], 0, 0, 0);
        __syncthreads();
    }
    if (bx == 0) {
        s1 += __shfl_xor(s1, 1, 64); s1 += __shfl_xor(s1, 2, 64);
        s2 += __shfl_xor(s2, 1, 64); s2 += __shfl_xor(s2, 2, 64);
        if ((tid & 3) == 0) {
            ws[OFF_SQ + sbase + srow] = s1;
            ws[OFF_SQ2 + sbase + srow] = s2;
        }
    }
#pragma unroll
    for (int nt = 0; nt < 4; nt++)
#pragma unroll
        for (int r = 0; r < 4; r++)
            C[(size_t)(w * 16 + grp * 4 + r) * 512 + bx * 64 + nt * 16 + c15] = acc[nt][r];
}

// ---- k4: main split-bf16 MFMA — M=128 tile (1024 blocks, 512 thr, 8 waves).
// Per wave per kcg: 8 global B loads + 16 LDS A reads feed 96 MFMAs (global
// loads per MFMA halved vs M=64). A frags loaded in two mt-halves to keep
// combined regs <= 256 (2 waves/SIMD). ti = bid&7 pins each XCD to one
// 128-row t-slice. All register arrays static-indexed (R9 lesson).
__global__ __launch_bounds__(512, 2) void main_mfma(const float* __restrict__ ws,
                                                    const float* __restrict__ bsc,
                                                    const float* __restrict__ Wo,
                                                    const float* __restrict__ bo,
                                                    float* __restrict__ logits) {
    __shared__ float kk[256];
    __shared__ __align__(16) short Ah[8][128 * 32];   // 64 KB
    __shared__ __align__(16) short Al[8][128 * 32];   // 64 KB
    __shared__ float mu_s[128], inv_s[128];
    __shared__ float part_s[8][128];
    int tid = threadIdx.x;
    int bidf = blockIdx.x;
    int ti = bidf & 7;
    int j = (bidf >> 3) & 63;
    int b = bidf >> 9;
    int t0 = ti << 7;
    int bj = (b << 6) | j;
    int rot8 = (bidf >> 3) & 7;
    if (tid < 256) kk[tid] = ws[OFF_K + bj * 256 + tid] + ws[OFF_K2 + bj * 256 + tid];
    int w = tid >> 6, l = tid & 63, c15 = l & 15, grp = l >> 4;
    int srow = tid >> 2, scol = (tid & 3) * 8;
    const float* qrow = ws + OFF_Q + (size_t)((b << 10) + t0 + srow) * 256 + scol;
    const float* q2row = ws + OFF_Q2 + (size_t)((b << 10) + t0 + srow) * 256 + scol;
    const bf16x8* bpk = (const bf16x8*)(bsc + BO_BPK);
    const float* UVQ = bsc + BO_UVQ;
    f32x4 acc[8][4];
#pragma unroll
    for (int mt = 0; mt < 8; mt++)
#pragma unroll
        for (int nt = 0; nt < 4; nt++) acc[mt][nt] = (f32x4){0.f, 0.f, 0.f, 0.f};
    float s1 = 0.f, s2 = 0.f;
    int ntg0 = w * 4;
    __syncthreads();   // kk ready
    // ---- stage ALL 8 K-chunks of the 128-row tile ----
#pragma unroll
    for (int kc = 0; kc < 8; kc++) {
        float q8[8], p8[8], kv[8];
        *(float4*)&q8[0] = *(const float4*)&qrow[kc * 32];
        *(float4*)&q8[4] = *(const float4*)&qrow[kc * 32 + 4];
        *(float4*)&p8[0] = *(const float4*)&q2row[kc * 32];
        *(float4*)&p8[4] = *(const float4*)&q2row[kc * 32 + 4];
        *(float4*)&kv[0] = *(const float4*)&kk[kc * 32 + scol];
        *(float4*)&kv[4] = *(const float4*)&kk[kc * 32 + scol + 4];
        bf16x8 vh, vl;
        short htmp[2], ltmp[2];
#pragma unroll
        for (int i = 0; i < 4; i++) {
            float a = (q8[2 * i] + p8[2 * i]) * kv[2 * i];
            float c = (q8[2 * i + 1] + p8[2 * i + 1]) * kv[2 * i + 1];
            s1 += a + c;
            s2 = fmaf(a, a, s2); s2 = fmaf(c, c, s2);
            split2(a, c, htmp, ltmp);
            vh[2 * i] = htmp[0]; vh[2 * i + 1] = htmp[1];
            vl[2 * i] = ltmp[0]; vl[2 * i + 1] = ltmp[1];
        }
        int ao = srow * 32 + scol;
        *(bf16x8*)&Ah[kc][ao] = vh;
        *(bf16x8*)&Al[kc][ao] = vl;
    }
    // LN stats (before the single barrier)
    s1 += __shfl_xor(s1, 1, 64); s1 += __shfl_xor(s1, 2, 64);
    s2 += __shfl_xor(s2, 1, 64); s2 += __shfl_xor(s2, 2, 64);
    if ((tid & 3) == 0) {
        int row = (b << 10) + t0 + srow;
        float sq = s1 + ws[OFF_SQ + row] + ws[OFF_SQ + 2048 + bj];
        float sq2 = s2 + ws[OFF_SQ2 + row] + ws[OFF_SQ2 + 2048 + bj];
        float muv = sq * (1.0f / 768.0f);
        float ex2 = sq2 * (1.0f / 768.0f);
        mu_s[srow] = muv;
        inv_s[srow] = 1.0f / sqrtf(ex2 - muv * muv + 1e-5f);
    }
    __syncthreads();   // the ONLY staging barrier
    // ---- MFMA: 8 K-chunks, kc order rotated per block (L2 de-lockstep) ----
#pragma unroll
    for (int ii = 0; ii < 8; ii++) {
        int kcg = (ii + rot8) & 7;           // runtime — addresses only
        bf16x8 bh[4], bl[4];
        const bf16x8* bpc = bpk + ((size_t)(kcg * 32 + ntg0) * 2) * 64 + l;
#pragma unroll
        for (int nt = 0; nt < 4; nt++) {
            bh[nt] = bpc[(size_t)nt * 128];
            bl[nt] = bpc[(size_t)nt * 128 + 64];
        }
#pragma unroll
        for (int half = 0; half < 2; half++) {
            bf16x8 afh[4], afl[4];
#pragma unroll
            for (int m4 = 0; m4 < 4; m4++) {
                int ao = ((half * 4 + m4) * 16 + c15) * 32 + grp * 8;
                afh[m4] = *(const bf16x8*)&Ah[kcg][ao];
                afl[m4] = *(const bf16x8*)&Al[kcg][ao];
            }
#pragma unroll
            for (int nt = 0; nt < 4; nt++) {
#pragma unroll
                for (int m4 = 0; m4 < 4; m4++)
                    acc[half * 4 + m4][nt] = __builtin_amdgcn_mfma_f32_16x16x32_bf16(afl[m4], bh[nt], acc[half * 4 + m4][nt], 0, 0, 0);
#pragma unroll
                for (int m4 = 0; m4 < 4; m4++)
                    acc[half * 4 + m4][nt] = __builtin_amdgcn_mfma_f32_16x16x32_bf16(afh[m4], bl[nt], acc[half * 4 + m4][nt], 0, 0, 0);
#pragma unroll
                for (int m4 = 0; m4 < 4; m4++)
                    acc[half * 4 + m4][nt] = __builtin_amdgcn_mfma_f32_16x16x32_bf16(afh[m4], bh[nt], acc[half * 4 + m4][nt], 0, 0, 0);
            }
        }
    }
    // ---- epilogue: lane owns 2 h-channels: U at ntg=4w+2a, V at 4w+2a+1 ----
    float wgu_r[2], wgv_r[2], cu_r[2], cv_r[2], wo_r[2], uk_r[2], vk_r[2];
    int h2[2];
#pragma unroll
    for (int a = 0; a < 2; a++) {
        int ntg = 4 * w + 2 * a;
        int h = ((ntg >> 3) << 6) | (((ntg >> 1) & 3) << 4) | c15;
        h2[a] = h;
        wgu_r[a] = ws[OFF_WGU + h]; wgv_r[a] = ws[OFF_WGV + h];
        cu_r[a] = ws[OFF_CU + h]; cv_r[a] = ws[OFF_CV + h];
        wo_r[a] = Wo[h];
        uk_r[a] = ws[OFF_UVK + (size_t)bj * 512 + h];
        vk_r[a] = ws[OFF_UVK + (size_t)bj * 512 + 256 + h];
    }
#pragma unroll
    for (int mt = 0; mt < 8; mt++) {
#pragma unroll
        for (int r4 = 0; r4 < 4; r4++) {
            int r = mt * 16 + grp * 4 + r4;
            int row = (b << 10) + t0 + r;
            float muv = mu_s[r], invv = inv_s[r];
            const float* uvq = UVQ + (size_t)row * 512;
            float part = 0.f;
#pragma unroll
            for (int a = 0; a < 2; a++) {
                float U = invv * (acc[mt][2 * a][r4] + uvq[h2[a]] + uk_r[a] - muv * wgu_r[a]) + cu_r[a];
                float V = invv * (acc[mt][2 * a + 1][r4] + uvq[256 + h2[a]] + vk_r[a] - muv * wgv_r[a]) + cv_r[a];
                part = fmaf(wo_r[a] * U, gelu_fast(V), part);
            }
            part += __shfl_xor(part, 1, 64);
            part += __shfl_xor(part, 2, 64);
            part += __shfl_xor(part, 4, 64);
            part += __shfl_xor(part, 8, 64);
            if (c15 == 0) part_s[w][r] = part;
        }
    }
    __syncthreads();
    if (tid < 128) {
        float v = bo[0];
#pragma unroll
        for (int ww = 0; ww < 8; ww++) v += part_s[ww][tid];
        logits[(size_t)((b << 10) + t0 + tid) * 64 + j] = v;
    }
}

// ---- k5: topk + softmax + bias expansion; 4 rows/block ----
__global__ __launch_bounds__(256) void topk_bias(const float* __restrict__ logits,
                                                 float* __restrict__ bias,
                                                 const int* __restrict__ p_cl,
                                                 const int* __restrict__ p_L) {
    int wv = threadIdx.x >> 6, lane = threadIdx.x & 63;
    int row = blockIdx.x * 4 + wv;
    int t = row & 1023;
    __shared__ float pcb[4][64];
    float L = logits[(size_t)row * 64 + lane];
    float mx = L;
#pragma unroll
    for (int off = 32; off > 0; off >>= 1) mx = fmaxf(mx, __shfl_xor(mx, off, 64));
    float e = expf(L - mx);
    float s = wave_reduce_add(e);
    pcb[wv][lane] = -8.0f * (1.0f - e / s);
    bool valid = (lane >= 5) && ((lane - 5) <= t);
    float val = (lane >= 5) ? (valid ? L : -INFINITY) : -INFINITY;
    int idv = (lane >= 5) ? lane : (1 << 28);
    unsigned long long selmask = 0x1Full;
    for (int it = 0; it < 11; it++) {
        float bv = val; int bi = idv;
#pragma unroll
        for (int off = 32; off > 0; off >>= 1) {
            float ov = __shfl_xor(bv, off, 64);
            int oi = __shfl_xor(bi, off, 64);
            if (ov > bv || (ov == bv && oi < bi)) { bv = ov; bi = oi; }
        }
        selmask |= 1ull << bi;
        if (lane == bi) { val = -INFINITY; idv = (1 << 27); }
    }
    int clen = p_cl[0], Lctx = p_L[0];
    int nch1 = (Lctx + clen - 1) / clen - 1;
    float* brow = bias + (size_t)row * Lctx;
    if ((Lctx & 3) == 0) {
        float4* brow4 = (float4*)brow;
        for (int q = lane; q < (Lctx >> 2); q += 64) {
            float o[4];
#pragma unroll
            for (int i = 0; i < 4; i++) {
                int ll = 4 * q + i;
                int c = min(min((unsigned)ll / (unsigned)clen, (unsigned)nch1), 63u);
                float v;
                if (ll > t) v = -1e30f;   // finite sentinel: ref -inf, diff must stay non-nan
                else if ((selmask >> c) & 1ull) v = 0.0f;
                else v = pcb[wv][c];
                o[i] = v;
            }
            brow4[q] = *(float4*)&o[0];
        }
    } else {
        for (int ll = lane; ll < Lctx; ll += 64) {
            int c = min(min((unsigned)ll / (unsigned)clen, (unsigned)nch1), 63u);
            float v;
            if (ll > t) v = -1e30f;
            else if ((selmask >> c) & 1ull) v = 0.0f;
            else v = pcb[wv][c];
            brow[ll] = v;
        }
    }
}

extern "C" void kernel_launch(void* const* d_in, const int* in_sizes, int n_in,
                              void* d_out, int out_size, void* d_ws, size_t ws_size,
                              hipStream_t stream) {
    const float* Q   = (const float*)d_in[0];
    const float* Kin = (const float*)d_in[1];
    const float* Wq  = (const float*)d_in[2];
    const float* Wk  = (const float*)d_in[3];
    const float* g   = (const float*)d_in[4];
    const float* lb  = (const float*)d_in[5];
    const float* Wu  = (const float*)d_in[6];
    const float* bu  = (const float*)d_in[7];
    const float* Wv  = (const float*)d_in[8];
    const float* bv  = (const float*)d_in[9];
    const float* Wo  = (const float*)d_in[10];
    const float* bo  = (const float*)d_in[11];
    const int* p_cl  = (const int*)d_in[12];
    const int* p_L   = (const int*)d_in[13];
    float* ws = (float*)d_ws;
    float* logits = (float*)d_out;
    float* bias = (float*)d_out + (size_t)2 * 1024 * 64;   // 131072

    prep<<<512, 256, 0, stream>>>(Wq, Wk, Wu, Wv, g, lb, bu, bv, ws, bias);
    proj_mfma<<<dim3(4, 68, 2), 256, 0, stream>>>(Q, Kin, bias, ws);
    uv_mfma<<<dim3(8, 34), 256, 0, stream>>>(ws, bias);
    main_mfma<<<1024, 512, 0, stream>>>(ws, bias, Wo, bo, logits);
    topk_bias<<<512, 256, 0, stream>>>(logits, bias, p_cl, p_L);
}

// Round 14
// 232.258 us; speedup vs baseline: 1.0698x; 1.0698x over previous
//
#include <hip/hip_runtime.h>
#include <hip/hip_bf16.h>
#include <math.h>

#define H3 768

// ---- ws layout (floats) ----
#define OFF_Q     0u        // 2048*256  (pre-summed q, atomic-accumulated)
#define OFF_K     524288u   // 128*256
#define OFF_UVK   557056u   // 128*512
#define OFF_SQ    622592u   // 2176 row sums (q rows 0..2047, k rows at 2048+bj)
#define OFF_SQ2   624768u   // 2176
#define OFF_WGU   626944u   // 256
#define OFF_WGV   627200u   // 256
#define OFF_CU    627456u   // 256
#define OFF_CV    627712u   // 256

// ---- scratch inside d_out's bias region (2097152 floats), all consumed
// before topk_bias overwrites it ----
#define BO_UVQ   0u          // 1048576  (2048x512 fp32)
#define BO_WQF   1048576u    // 262144   (Wq frags hi/lo, NTG=16, K=1024)
#define BO_WKF   1310720u    // 262144
#define BO_BPK   1572864u    // 131072   (qk-weight frags, NTG=32, K=256)
#define BO_WQBF  1703936u    // 131072
#define BO_WKBF  1835008u    // 131072   end 1966080 < 2097152

typedef __attribute__((ext_vector_type(8))) short bf16x8;
typedef __attribute__((ext_vector_type(4))) float f32x4;

__device__ __forceinline__ float bf2f(short s) {
    return __uint_as_float(((unsigned)(unsigned short)s) << 16);
}
union bfu { __hip_bfloat162 h; short2 s; };
__device__ __forceinline__ void split2(float a, float b, short* hi2, short* lo2) {
    bfu h; h.h = __float22bfloat162_rn(float2{a, b});
    float fa = bf2f(h.s.x), fb = bf2f(h.s.y);
    bfu l; l.h = __float22bfloat162_rn(float2{a - fa, b - fb});
    hi2[0] = h.s.x; hi2[1] = h.s.y;
    lo2[0] = l.s.x; lo2[1] = l.s.y;
}
__device__ __forceinline__ void split8(const float* v, bf16x8* vh, bf16x8* vl) {
    short h2[2], l2[2];
#pragma unroll
    for (int i = 0; i < 4; i++) {
        split2(v[2 * i], v[2 * i + 1], h2, l2);
        (*vh)[2 * i] = h2[0]; (*vh)[2 * i + 1] = h2[1];
        (*vl)[2 * i] = l2[0]; (*vl)[2 * i + 1] = l2[1];
    }
}

// branchless exact-gelu via A&S 7.1.26 erf (abs err ~1.5e-7)
__device__ __forceinline__ float gelu_fast(float v) {
    float ar = v * 0.70710678118654752440f;
    float a = fabsf(ar);
    float t = __builtin_amdgcn_rcpf(fmaf(0.3275911f, a, 1.0f));
    float p = fmaf(fmaf(fmaf(fmaf(1.061405429f, t, -1.453152027f), t,
                             1.421413741f), t, -0.284496736f), t, 0.254829592f) * t;
    float e = __expf(-ar * ar);
    float er = fmaf(-p, e, 1.0f);
    er = copysignf(er, ar);
    return 0.5f * v * (1.0f + er);
}

__device__ __forceinline__ float wave_reduce_add(float v) {
#pragma unroll
    for (int off = 32; off > 0; off >>= 1) v += __shfl_xor(v, off, 64);
    return v;
}

// ---- k1: prep — per-h scalars + weight frag scatters + q/K zeroing ----
__global__ __launch_bounds__(256) void prep(const float* __restrict__ Wq,
                                            const float* __restrict__ Wk,
                                            const float* __restrict__ Wu,
                                            const float* __restrict__ Wv,
                                            const float* __restrict__ g,
                                            const float* __restrict__ lb,
                                            const float* __restrict__ bu,
                                            const float* __restrict__ bv,
                                            float* __restrict__ ws,
                                            float* __restrict__ bsc) {
    int tid = threadIdx.x;
    int bid = blockIdx.x;
    if (bid >= 512) {
        ws[(bid - 512) * 256 + tid] = 0.0f;   // zero q/K region [0, 557056)
        return;
    }
    if (bid < 64) {
        int h = bid * 4 + (tid >> 6);
        int lane = tid & 63;
        float su = 0.f, sv = 0.f, tu = 0.f, tv = 0.f;
#pragma unroll
        for (int i = 0; i < 12; i++) {
            int c = lane + 64 * i;
            float gg = g[c], bb = lb[c];
            float wu = Wu[h * H3 + c], wv = Wv[h * H3 + c];
            su += wu * gg; sv += wv * gg; tu += wu * bb; tv += wv * bb;
        }
        su = wave_reduce_add(su); sv = wave_reduce_add(sv);
        tu = wave_reduce_add(tu); tv = wave_reduce_add(tv);
        if (lane == 0) {
            ws[OFF_WGU + h] = su; ws[OFF_WGV + h] = sv;
            ws[OFF_CU + h] = tu + bu[h]; ws[OFF_CV + h] = tv + bv[h];
        }
        return;
    }
    float v8[8];
    bf16x8 vh, vl;
    if (bid < 320) {
        // WqF (64..191) / WkF (192..319): N=256, K=1024, NTG=16
        const float* W; bf16x8* dst;
        int idx;
        if (bid < 192) { idx = (bid - 64) * 256 + tid; W = Wq; dst = (bf16x8*)(bsc + BO_WQF); }
        else { idx = (bid - 192) * 256 + tid; W = Wk; dst = (bf16x8*)(bsc + BO_WKF); }
        int n = idx >> 7, k8 = idx & 127;
        const float* src = W + (size_t)n * 1024 + k8 * 8;
        *(float4*)&v8[0] = *(const float4*)src;
        *(float4*)&v8[4] = *(const float4*)(src + 4);
        split8(v8, &vh, &vl);
        int kc = k8 >> 2, grp = k8 & 3, lane = grp * 16 + (n & 15), ntg = n >> 4;
        size_t s0 = ((size_t)(kc * 16 + ntg) * 2) * 64 + lane;
        dst[s0] = vh; dst[s0 + 64] = vl;
        return;
    }
    // N=512, K=256, NTG=32 frag matrices from Wu/Wv*g
    int idx, c0;
    bf16x8* dst;
    int n;
    if (bid < 384) {        // WQBf
        idx = (bid - 320) * 256 + tid;
        n = idx >> 5; c0 = (idx & 31) * 8;
        dst = (bf16x8*)(bsc + BO_WQBF);
    } else if (bid < 448) { // WKBf
        idx = (bid - 384) * 256 + tid;
        n = idx >> 5; c0 = 256 + (idx & 31) * 8;
        dst = (bf16x8*)(bsc + BO_WKBF);
    } else {                // BPK (interleaved U/V n-mapping)
        idx = (bid - 448) * 256 + tid;
        n = idx >> 5; c0 = 512 + (idx & 31) * 8;
        dst = (bf16x8*)(bsc + BO_BPK);
    }
    int h, uv;
    if (bid < 448) { uv = (n < 256) ? 0 : 1; h = (n < 256) ? n : n - 256; }
    else {
        int ntg0 = n >> 4, cc = n & 15;
        uv = ntg0 & 1;
        h = ((ntg0 >> 3) << 6) | (((ntg0 >> 1) & 3) << 4) | cc;
    }
    const float* W = uv ? Wv : Wu;
#pragma unroll
    for (int i = 0; i < 8; i++) v8[i] = W[(size_t)h * H3 + c0 + i] * g[c0 + i];
    split8(v8, &vh, &vl);
    int k8 = (c0 & 255) >> 3;
    int kc = k8 >> 2, grp = k8 & 3, lane = grp * 16 + (n & 15), ntg = n >> 4;
    size_t s0 = ((size_t)(kc * 32 + ntg) * 2) * 64 + lane;
    dst[s0] = vh; dst[s0 + 64] = vl;
}

// ---- k2: projection MFMA, K-split x2, atomicAdd accumulate (exactly 2
// commutative fp32 adds per element -> bitwise deterministic) ----
__global__ __launch_bounds__(256) void proj_mfma(const float* __restrict__ Q,
                                                 const float* __restrict__ Kin,
                                                 const float* __restrict__ bsc,
                                                 float* __restrict__ ws) {
    __shared__ __align__(16) short Ah[2][32 * 40], Al[2][32 * 40];
    int tid = threadIdx.x, bx = blockIdx.x, by = blockIdx.y, ks = blockIdx.z;
    const float* A; float* C; const bf16x8* BF;
    if (by < 64) {
        A = Q + (size_t)by * 32 * 1024;
        C = ws + OFF_Q + (size_t)by * 32 * 256;
        BF = (const bf16x8*)(bsc + BO_WQF);
    } else {
        A = Kin + (size_t)(by - 64) * 32 * 1024;
        C = ws + OFF_K + (size_t)(by - 64) * 32 * 256;
        BF = (const bf16x8*)(bsc + BO_WKF);
    }
    int w = tid >> 6, l = tid & 63, c15 = l & 15, grp = l >> 4;
    int mt = w & 1, np = w >> 1;
    int srow = tid >> 3, scol = (tid & 7) * 4;
    const float* arow = A + (size_t)srow * 1024 + ks * 512 + scol;
    f32x4 acc[2];
    acc[0] = (f32x4){0.f, 0.f, 0.f, 0.f};
    acc[1] = (f32x4){0.f, 0.f, 0.f, 0.f};
    float4 a4 = *(const float4*)&arow[0];
    for (int kc = 0; kc < 16; kc++) {
        int pb = kc & 1;
        short h4[4], l4[4];
        split2(a4.x, a4.y, &h4[0], &l4[0]);
        split2(a4.z, a4.w, &h4[2], &l4[2]);
        int ao = srow * 40 + scol;
        *(short4*)&Ah[pb][ao] = *(short4*)&h4[0];
        *(short4*)&Al[pb][ao] = *(short4*)&l4[0];
        if (kc < 15) a4 = *(const float4*)&arow[(kc + 1) * 32];
        __syncthreads();
        int fo = (mt * 16 + c15) * 40 + grp * 8;
        bf16x8 afh = *(const bf16x8*)&Ah[pb][fo];
        bf16x8 afl = *(const bf16x8*)&Al[pb][fo];
        int kcg = ks * 16 + kc;
        bf16x8 bh[2], bl[2];
#pragma unroll
        for (int i = 0; i < 2; i++) {
            int ntg = bx * 4 + 2 * np + i;
            size_t fi = ((size_t)(kcg * 16 + ntg) * 2) * 64 + l;
            bh[i] = BF[fi]; bl[i] = BF[fi + 64];
        }
#pragma unroll
        for (int i = 0; i < 2; i++)
            acc[i] = __builtin_amdgcn_mfma_f32_16x16x32_bf16(afl, bh[i], acc[i], 0, 0, 0);
#pragma unroll
        for (int i = 0; i < 2; i++)
            acc[i] = __builtin_amdgcn_mfma_f32_16x16x32_bf16(afh, bl[i], acc[i], 0, 0, 0);
#pragma unroll
        for (int i = 0; i < 2; i++)
            acc[i] = __builtin_amdgcn_mfma_f32_16x16x32_bf16(afh, bh[i], acc[i], 0, 0, 0);
    }
#pragma unroll
    for (int r = 0; r < 4; r++) {
        int rloc = mt * 16 + grp * 4 + r;
#pragma unroll
        for (int i = 0; i < 2; i++)
            atomicAdd(&C[(size_t)rloc * 256 + bx * 64 + (2 * np + i) * 16 + c15], acc[i][r]);
    }
}

// ---- k3: UV GEMM via MFMA (single pre-summed A) + fused row stats ----
__global__ __launch_bounds__(256) void uv_mfma(float* __restrict__ ws,
                                               float* __restrict__ bsc) {
    __shared__ __align__(16) short Ah[64 * 40], Al[64 * 40];
    int tid = threadIdx.x, bx = blockIdx.x, by = blockIdx.y;
    const float* A; float* C; const bf16x8* BF; int sbase;
    if (by < 32) {
        A = ws + OFF_Q + (size_t)by * 64 * 256;
        C = bsc + BO_UVQ + (size_t)by * 64 * 512;
        BF = (const bf16x8*)(bsc + BO_WQBF);
        sbase = by * 64;
    } else {
        A = ws + OFF_K + (size_t)(by - 32) * 64 * 256;
        C = ws + OFF_UVK + (size_t)(by - 32) * 64 * 512;
        BF = (const bf16x8*)(bsc + BO_WKBF);
        sbase = 2048 + (by - 32) * 64;
    }
    int w = tid >> 6, l = tid & 63, c15 = l & 15, grp = l >> 4;
    int srow = tid >> 2, scol = (tid & 3) * 8;
    f32x4 acc[4];
#pragma unroll
    for (int nt = 0; nt < 4; nt++) acc[nt] = (f32x4){0.f, 0.f, 0.f, 0.f};
    float s1 = 0.f, s2 = 0.f;
    for (int kc = 0; kc < 8; kc++) {
        float v8[8];
        const float* src = &A[(size_t)srow * 256 + kc * 32 + scol];
        *(float4*)&v8[0] = *(const float4*)src;
        *(float4*)&v8[4] = *(const float4*)(src + 4);
        if (bx == 0) {
#pragma unroll
            for (int i = 0; i < 8; i++) { s1 += v8[i]; s2 = fmaf(v8[i], v8[i], s2); }
        }
        bf16x8 vh, vl;
        split8(v8, &vh, &vl);
        int ao = srow * 40 + scol;
        *(bf16x8*)&Ah[ao] = vh;
        *(bf16x8*)&Al[ao] = vl;
        __syncthreads();
        int fo = (w * 16 + c15) * 40 + grp * 8;
        bf16x8 afh = *(const bf16x8*)&Ah[fo];
        bf16x8 afl = *(const bf16x8*)&Al[fo];
        bf16x8 bh[4], bl[4];
#pragma unroll
        for (int nt = 0; nt < 4; nt++) {
            int ntg = bx * 4 + nt;
            size_t fi = ((size_t)(kc * 32 + ntg) * 2) * 64 + l;
            bh[nt] = BF[fi]; bl[nt] = BF[fi + 64];
        }
#pragma unroll
        for (int nt = 0; nt < 4; nt++)
            acc[nt] = __builtin_amdgcn_mfma_f32_16x16x32_bf16(afl, bh[nt], acc[nt], 0, 0, 0);
#pragma unroll
        for (int nt = 0; nt < 4; nt++)
            acc[nt] = __builtin_amdgcn_mfma_f32_16x16x32_bf16(afh, bl[nt], acc[nt], 0, 0, 0);
#pragma unroll
        for (int nt = 0; nt < 4; nt++)
            acc[nt] = __builtin_amdgcn_mfma_f32_16x16x32_bf16(afh, bh[nt], acc[nt], 0, 0, 0);
        __syncthreads();
    }
    if (bx == 0) {
        s1 += __shfl_xor(s1, 1, 64); s1 += __shfl_xor(s1, 2, 64);
        s2 += __shfl_xor(s2, 1, 64); s2 += __shfl_xor(s2, 2, 64);
        if ((tid & 3) == 0) {
            ws[OFF_SQ + sbase + srow] = s1;
            ws[OFF_SQ2 + sbase + srow] = s2;
        }
    }
#pragma unroll
    for (int nt = 0; nt < 4; nt++)
#pragma unroll
        for (int r = 0; r < 4; r++)
            C[(size_t)(w * 16 + grp * 4 + r) * 512 + bx * 64 + nt * 16 + c15] = acc[nt][r];
}

// ---- k4: main split-bf16 MFMA — R12 exact shape (best: 131.5us), single
// pre-summed q read. 256 thr, nt=8/wave, single barrier, XCD swizzle + rot8.
// All register arrays static-indexed (R9 lesson).
__global__ __launch_bounds__(256, 2) void main_mfma(const float* __restrict__ ws,
                                                    const float* __restrict__ bsc,
                                                    const float* __restrict__ Wo,
                                                    const float* __restrict__ bo,
                                                    float* __restrict__ logits) {
    __shared__ float kk[256];
    __shared__ __align__(16) short Ah[8][64 * 32];   // 32 KB
    __shared__ __align__(16) short Al[8][64 * 32];   // 32 KB
    __shared__ float mu_s[64], inv_s[64];
    __shared__ float part_s[4][64];
    int tid = threadIdx.x;
    int bidf = blockIdx.x;
    int ti = ((bidf & 7) << 1) | ((bidf >> 3) & 1);
    int j = (bidf >> 4) & 63;
    int b = bidf >> 10;
    int t0 = ti << 6;
    int bj = (b << 6) | j;
    int rot8 = bidf & 7;
    kk[tid] = ws[OFF_K + bj * 256 + tid];
    int w = tid >> 6, l = tid & 63, c15 = l & 15, grp = l >> 4;
    int srow = tid >> 2, scol = (tid & 3) * 8;
    const float* qrow = ws + OFF_Q + (size_t)((b << 10) + t0 + srow) * 256 + scol;
    const bf16x8* bpk = (const bf16x8*)(bsc + BO_BPK);
    const float* UVQ = bsc + BO_UVQ;
    f32x4 acc[4][8];
#pragma unroll
    for (int mt = 0; mt < 4; mt++)
#pragma unroll
        for (int nt = 0; nt < 8; nt++) acc[mt][nt] = (f32x4){0.f, 0.f, 0.f, 0.f};
    float s1 = 0.f, s2 = 0.f;
    int ntg0 = w * 8;
    __syncthreads();   // kk ready
    // ---- stage ALL 8 K-chunks (q * kk -> hi/lo bf16) ----
#pragma unroll
    for (int kc = 0; kc < 8; kc++) {
        float q8[8], kv[8];
        *(float4*)&q8[0] = *(const float4*)&qrow[kc * 32];
        *(float4*)&q8[4] = *(const float4*)&qrow[kc * 32 + 4];
        *(float4*)&kv[0] = *(const float4*)&kk[kc * 32 + scol];
        *(float4*)&kv[4] = *(const float4*)&kk[kc * 32 + scol + 4];
        bf16x8 vh, vl;
        short htmp[2], ltmp[2];
#pragma unroll
        for (int i = 0; i < 4; i++) {
            float a = q8[2 * i] * kv[2 * i];
            float c = q8[2 * i + 1] * kv[2 * i + 1];
            s1 += a + c;
            s2 = fmaf(a, a, s2); s2 = fmaf(c, c, s2);
            split2(a, c, htmp, ltmp);
            vh[2 * i] = htmp[0]; vh[2 * i + 1] = htmp[1];
            vl[2 * i] = ltmp[0]; vl[2 * i + 1] = ltmp[1];
        }
        int ao = srow * 32 + scol;
        *(bf16x8*)&Ah[kc][ao] = vh;
        *(bf16x8*)&Al[kc][ao] = vl;
    }
    // LN stats (before the single barrier)
    s1 += __shfl_xor(s1, 1, 64); s1 += __shfl_xor(s1, 2, 64);
    s2 += __shfl_xor(s2, 1, 64); s2 += __shfl_xor(s2, 2, 64);
    if ((tid & 3) == 0) {
        int row = (b << 10) + t0 + srow;
        float sq = s1 + ws[OFF_SQ + row] + ws[OFF_SQ + 2048 + bj];
        float sq2 = s2 + ws[OFF_SQ2 + row] + ws[OFF_SQ2 + 2048 + bj];
        float muv = sq * (1.0f / 768.0f);
        float ex2 = sq2 * (1.0f / 768.0f);
        mu_s[srow] = muv;
        inv_s[srow] = 1.0f / sqrtf(ex2 - muv * muv + 1e-5f);
    }
    __syncthreads();   // the ONLY staging barrier
    // ---- MFMA: 8 K-chunks, kc order rotated per block (L2 de-lockstep) ----
#pragma unroll
    for (int ii = 0; ii < 8; ii++) {
        int kcg = (ii + rot8) & 7;           // runtime — addresses only
        bf16x8 afh[4], afl[4];
#pragma unroll
        for (int mt = 0; mt < 4; mt++) {
            int ao = (mt * 16 + c15) * 32 + grp * 8;
            afh[mt] = *(const bf16x8*)&Ah[kcg][ao];
            afl[mt] = *(const bf16x8*)&Al[kcg][ao];
        }
        const bf16x8* bpc = bpk + ((size_t)(kcg * 32 + ntg0) * 2) * 64 + l;
#pragma unroll
        for (int nt = 0; nt < 8; nt++) {
            bf16x8 bh = bpc[(size_t)nt * 128];
            bf16x8 bl = bpc[(size_t)nt * 128 + 64];
#pragma unroll
            for (int mt = 0; mt < 4; mt++)
                acc[mt][nt] = __builtin_amdgcn_mfma_f32_16x16x32_bf16(afl[mt], bh, acc[mt][nt], 0, 0, 0);
#pragma unroll
            for (int mt = 0; mt < 4; mt++)
                acc[mt][nt] = __builtin_amdgcn_mfma_f32_16x16x32_bf16(afh[mt], bl, acc[mt][nt], 0, 0, 0);
#pragma unroll
            for (int mt = 0; mt < 4; mt++)
                acc[mt][nt] = __builtin_amdgcn_mfma_f32_16x16x32_bf16(afh[mt], bh, acc[mt][nt], 0, 0, 0);
        }
    }
    // ---- epilogue: lane owns 4 h-channels (a=0..3): U at nt=2a, V at nt=2a+1;
    // h = (w<<6)|(a<<4)|c15 since ntg = w*8+2a ----
    float wgu_r[4], wgv_r[4], cu_r[4], cv_r[4], wo_r[4], uk_r[4], vk_r[4];
    int h4[4];
#pragma unroll
    for (int a = 0; a < 4; a++) {
        int h = (w << 6) | (a << 4) | c15;
        h4[a] = h;
        wgu_r[a] = ws[OFF_WGU + h]; wgv_r[a] = ws[OFF_WGV + h];
        cu_r[a] = ws[OFF_CU + h]; cv_r[a] = ws[OFF_CV + h];
        wo_r[a] = Wo[h];
        uk_r[a] = ws[OFF_UVK + (size_t)bj * 512 + h];
        vk_r[a] = ws[OFF_UVK + (size_t)bj * 512 + 256 + h];
    }
#pragma unroll
    for (int mt = 0; mt < 4; mt++) {
#pragma unroll
        for (int r4 = 0; r4 < 4; r4++) {
            int r = mt * 16 + grp * 4 + r4;
            int row = (b << 10) + t0 + r;
            float muv = mu_s[r], invv = inv_s[r];
            const float* uvq = UVQ + (size_t)row * 512;
            float part = 0.f;
#pragma unroll
            for (int a = 0; a < 4; a++) {
                float U = invv * (acc[mt][2 * a][r4] + uvq[h4[a]] + uk_r[a] - muv * wgu_r[a]) + cu_r[a];
                float V = invv * (acc[mt][2 * a + 1][r4] + uvq[256 + h4[a]] + vk_r[a] - muv * wgv_r[a]) + cv_r[a];
                part = fmaf(wo_r[a] * U, gelu_fast(V), part);
            }
            part += __shfl_xor(part, 1, 64);
            part += __shfl_xor(part, 2, 64);
            part += __shfl_xor(part, 4, 64);
            part += __shfl_xor(part, 8, 64);
            if (c15 == 0) part_s[w][r] = part;
        }
    }
    __syncthreads();
    if (tid < 64) {
        float v = bo[0] + part_s[0][tid] + part_s[1][tid] + part_s[2][tid] + part_s[3][tid];
        logits[(size_t)((b << 10) + t0 + tid) * 64 + j] = v;
    }
}

// ---- k5: topk + softmax + bias expansion; 4 rows/block; pow2 fast path ----
__global__ __launch_bounds__(256) void topk_bias(const float* __restrict__ logits,
                                                 float* __restrict__ bias,
                                                 const int* __restrict__ p_cl,
                                                 const int* __restrict__ p_L) {
    int wv = threadIdx.x >> 6, lane = threadIdx.x & 63;
    int row = blockIdx.x * 4 + wv;
    int t = row & 1023;
    __shared__ float pcb[4][64];
    float L = logits[(size_t)row * 64 + lane];
    float mx = L;
#pragma unroll
    for (int off = 32; off > 0; off >>= 1) mx = fmaxf(mx, __shfl_xor(mx, off, 64));
    float e = expf(L - mx);
    float s = wave_reduce_add(e);
    pcb[wv][lane] = -8.0f * (1.0f - e / s);
    bool valid = (lane >= 5) && ((lane - 5) <= t);
    float val = (lane >= 5) ? (valid ? L : -INFINITY) : -INFINITY;
    int idv = (lane >= 5) ? lane : (1 << 28);
    unsigned long long selmask = 0x1Full;
    for (int it = 0; it < 11; it++) {
        float bv = val; int bi = idv;
#pragma unroll
        for (int off = 32; off > 0; off >>= 1) {
            float ov = __shfl_xor(bv, off, 64);
            int oi = __shfl_xor(bi, off, 64);
            if (ov > bv || (ov == bv && oi < bi)) { bv = ov; bi = oi; }
        }
        selmask |= 1ull << bi;
        if (lane == bi) { val = -INFINITY; idv = (1 << 27); }
    }
    int clen = p_cl[0], Lctx = p_L[0];
    int nch1 = (Lctx + clen - 1) / clen - 1;
    bool p2 = (clen & (clen - 1)) == 0;
    int sh = 31 - __clz(clen);
    float* brow = bias + (size_t)row * Lctx;
    if ((Lctx & 3) == 0) {
        float4* brow4 = (float4*)brow;
        for (int q = lane; q < (Lctx >> 2); q += 64) {
            float o[4];
#pragma unroll
            for (int i = 0; i < 4; i++) {
                int ll = 4 * q + i;
                unsigned cq = p2 ? ((unsigned)ll >> sh) : ((unsigned)ll / (unsigned)clen);
                int c = min(min(cq, (unsigned)nch1), 63u);
                float v;
                if (ll > t) v = -1e30f;   // finite sentinel: ref -inf, diff must stay non-nan
                else if ((selmask >> c) & 1ull) v = 0.0f;
                else v = pcb[wv][c];
                o[i] = v;
            }
            brow4[q] = *(float4*)&o[0];
        }
    } else {
        for (int ll = lane; ll < Lctx; ll += 64) {
            unsigned cq = p2 ? ((unsigned)ll >> sh) : ((unsigned)ll / (unsigned)clen);
            int c = min(min(cq, (unsigned)nch1), 63u);
            float v;
            if (ll > t) v = -1e30f;
            else if ((selmask >> c) & 1ull) v = 0.0f;
            else v = pcb[wv][c];
            brow[ll] = v;
        }
    }
}

extern "C" void kernel_launch(void* const* d_in, const int* in_sizes, int n_in,
                              void* d_out, int out_size, void* d_ws, size_t ws_size,
                              hipStream_t stream) {
    const float* Q   = (const float*)d_in[0];
    const float* Kin = (const float*)d_in[1];
    const float* Wq  = (const float*)d_in[2];
    const float* Wk  = (const float*)d_in[3];
    const float* g   = (const float*)d_in[4];
    const float* lb  = (const float*)d_in[5];
    const float* Wu  = (const float*)d_in[6];
    const float* bu  = (const float*)d_in[7];
    const float* Wv  = (const float*)d_in[8];
    const float* bv  = (const float*)d_in[9];
    const float* Wo  = (const float*)d_in[10];
    const float* bo  = (const float*)d_in[11];
    const int* p_cl  = (const int*)d_in[12];
    const int* p_L   = (const int*)d_in[13];
    float* ws = (float*)d_ws;
    float* logits = (float*)d_out;
    float* bias = (float*)d_out + (size_t)2 * 1024 * 64;   // 131072

    prep<<<2688, 256, 0, stream>>>(Wq, Wk, Wu, Wv, g, lb, bu, bv, ws, bias);
    proj_mfma<<<dim3(4, 68, 2), 256, 0, stream>>>(Q, Kin, bias, ws);
    uv_mfma<<<dim3(8, 34), 256, 0, stream>>>(ws, bias);
    main_mfma<<<2048, 256, 0, stream>>>(ws, bias, Wo, bo, logits);
    topk_bias<<<512, 256, 0, stream>>>(logits, bias, p_cl, p_L);
}